// Round 8
// baseline (457.488 us; speedup 1.0000x reference)
//
#include <hip/hip_runtime.h>
#include <cmath>

#define SLEN 2048

typedef __bf16 bf16x8 __attribute__((ext_vector_type(8)));
typedef float  f32x4  __attribute__((ext_vector_type(4)));

__device__ inline void gld16(const void* g, void* l) {
    __builtin_amdgcn_global_load_lds(
        (const __attribute__((address_space(1))) void*)(uintptr_t)g,
        (__attribute__((address_space(3))) void*)(unsigned)(uintptr_t)l, 16, 0, 0);
}

// ---------------------------------------------------------------------------
// One-launch fp32->bf16 convert of all 9 inputs (segment table by value).
// ---------------------------------------------------------------------------
struct CvArgs {
    const float* src[9];
    __bf16*      dst[9];
    long         cum[10];
};
__global__ __launch_bounds__(256)
void convert_all(CvArgs a) {
    long i8 = ((long)blockIdx.x * 256 + threadIdx.x) * 8;
    if (i8 >= a.cum[9]) return;
    int s = 0;
#pragma unroll
    for (int k = 1; k < 9; k++) if (i8 >= a.cum[k]) s = k;
    long loc = i8 - a.cum[s];
    const float* sp = a.src[s] + loc;
    float4 u0 = *(const float4*)(sp);
    float4 u1 = *(const float4*)(sp + 4);
    bf16x8 o;
    o[0] = (__bf16)u0.x; o[1] = (__bf16)u0.y; o[2] = (__bf16)u0.z; o[3] = (__bf16)u0.w;
    o[4] = (__bf16)u1.x; o[5] = (__bf16)u1.y; o[6] = (__bf16)u1.z; o[7] = (__bf16)u1.w;
    *(bf16x8*)(a.dst[s] + loc) = o;
}

struct Outs { __bf16* a; __bf16* b; __bf16* c; float* f; };

// ---------------------------------------------------------------------------
// Old NT GEMM, 128x128x64 tiles, 4 waves (proven 2-phase config).  Used only
// for gemm1 (N=2112, mode 8 incl. k-rope strip + broadcast).
// ---------------------------------------------------------------------------
__global__ __launch_bounds__(256, 3)
void gemm_nt(const __bf16* __restrict__ A, const __bf16* __restrict__ B,
             Outs o, const int* __restrict__ positions,
             int M, int N, int K, int mode, float scale) {
    __shared__ __bf16 As[128 * 64];
    __shared__ __bf16 Bs[128 * 64];
    int tid = threadIdx.x;
    int wave = tid >> 6, lane = tid & 63;
    int lane15 = lane & 15, quad = lane >> 4;
    int ri = lane >> 3, ci = lane & 7;
    int cg = ci ^ ri;
    int m0 = blockIdx.x * 128, n0 = blockIdx.y * 128;
    int wm = (wave & 1) * 64, wn = (wave >> 1) * 64;
    f32x4 acc[4][4] = {};

    for (int k0 = 0; k0 < K; k0 += 64) {
#pragma unroll
        for (int t = 0; t < 4; t++) {
            int rr = wave * 32 + t * 8;
            int r = rr + ri;
            gld16(A + (size_t)(m0 + r) * K + k0 + cg * 8, As + rr * 64);
            int br = n0 + r; if (br > N - 1) br = N - 1;
            gld16(B + (size_t)br * K + k0 + cg * 8, Bs + rr * 64);
        }
        __syncthreads();
#pragma unroll
        for (int kk = 0; kk < 64; kk += 32) {
            int jb = kk >> 3;
            bf16x8 af[4], bfr[4];
#pragma unroll
            for (int mt = 0; mt < 4; mt++) {
                int rA = wm + mt * 16 + lane15;
                af[mt] = *(bf16x8*)(As + rA * 64 + (((jb + quad) ^ (rA & 7)) << 3));
            }
#pragma unroll
            for (int nt = 0; nt < 4; nt++) {
                int rB = wn + nt * 16 + lane15;
                bfr[nt] = *(bf16x8*)(Bs + rB * 64 + (((jb + quad) ^ (rB & 7)) << 3));
            }
#pragma unroll
            for (int mt = 0; mt < 4; mt++)
#pragma unroll
                for (int nt = 0; nt < 4; nt++)
                    acc[mt][nt] = __builtin_amdgcn_mfma_f32_16x16x32_bf16(
                        af[mt], bfr[nt], acc[mt][nt], 0, 0, 0);
        }
        __syncthreads();
    }

    const float KLOG = 13.287712379549449f / 32.0f;  // log2(10000)/32

    if (mode == 8 && n0 == 2048) {                     // k-rope + broadcast
        if (wn == 0) {
#pragma unroll
            for (int mt = 0; mt < 4; mt++) {
                int row = m0 + wm + mt * 16 + quad * 4;
#pragma unroll
                for (int nt = 0; nt < 2; nt++) {
                    int i = nt * 16 + lane15;          // 0..31
                    float inv = exp2f(-(float)i * KLOG);
#pragma unroll
                    for (int r = 0; r < 4; r++) {
                        int tok = row + r;
                        float p = (float)positions[tok & (SLEN - 1)];
                        float sn, cs; sincosf(p * inv, &sn, &cs);
                        float t1 = acc[mt][nt][r], t2 = acc[mt][nt + 2][r];
                        float rot1 = t1 * cs - t2 * sn;
                        float rot2 = t2 * cs + t1 * sn;
                        size_t ob = (size_t)tok * 3072 + 128;
#pragma unroll
                        for (int hh = 0; hh < 16; hh++) {
                            o.c[ob + hh * 192 + i]      = (__bf16)rot1;
                            o.c[ob + hh * 192 + 32 + i] = (__bf16)rot2;
                        }
                    }
                }
            }
        }
        return;
    }

#pragma unroll
    for (int mt = 0; mt < 4; mt++) {
        int row = m0 + wm + mt * 16 + quad * 4;
#pragma unroll
        for (int nt = 0; nt < 4; nt++) {
            int col = n0 + wn + nt * 16 + lane15;
            if (col < N) {
#pragma unroll
                for (int r = 0; r < 4; r++) {
                    float v = acc[mt][nt][r];
                    size_t rw = (size_t)(row + r);
                    if (mode == 8) {
                        if (col < 1536) o.a[rw * 1536 + col] = (__bf16)v;
                        else            o.b[rw * 512 + col - 1536] = (__bf16)v;
                    }
                }
            }
        }
    }
}

// ---------------------------------------------------------------------------
// 8-phase-style NT GEMM (T3+T4+T5+T1): 128x256x64 tiles, 8 waves (2M x 4N,
// each 64x64 out), 3-buffer LDS ring (144 KiB -> 2-K-tile prefetch distance).
// Per K-tile: 2 phases, each {8 ds_read_b128 | issue stage unit(s) for t+2 ->
// barrier -> lgkmcnt(0) -> setprio(1) + 16 MFMA -> barrier}.  Counted
// s_waitcnt vmcnt(6) ONCE per K-tile (never 0 in steady state): t+1's 6 loads
// (issued during t-1) are the 7th-12th oldest, so they have landed; t+2's 6
// stay in flight across the barrier.  Buffer-hazard: stage(t+2)->buf[(t+2)%3]
// was last read at K-tile t-1 whose reads drain (lgkmcnt) before its end
// barrier; stage issue follows that barrier.
// Modes: 2 fp32-out, 9 q_all scatter + q-rope, 10 k_all scatter + V transpose.
// Requires N % 256 == 0, K % 128 == 0, grid % 8 == 0.
// ---------------------------------------------------------------------------
__global__ __launch_bounds__(512, 2)
void gemm8p(const __bf16* __restrict__ A, const __bf16* __restrict__ B,
            Outs o, const int* __restrict__ positions,
            int N, int K, int mode, float scale) {
    __shared__ __bf16 As[3][128 * 64];
    __shared__ __bf16 Bs[3][256 * 64];
    int tid = threadIdx.x;
    int wave = tid >> 6, lane = tid & 63;
    int lane15 = lane & 15, quad = lane >> 4;
    int wr = wave >> 2, wc = wave & 3;

    // T1: bijective XCD-chunked remap, m-fastest within chunk.
    int nwg = gridDim.x;
    int chnk = nwg >> 3;
    int bid = blockIdx.x;
    int wg = (bid & 7) * chnk + (bid >> 3);
    int m0 = (wg & 31) * 128;                  // M = 4096 fixed
    int n0 = (wg >> 5) * 256;

    f32x4 acc[4][4] = {};
    int NT = K >> 6;

    auto stageA = [&](int kt, int buf) {       // 2 gld16: all of A 128x64
#pragma unroll
        for (int u = 0; u < 2; u++) {
            int slot = u * 512 + wave * 64 + lane;
            int r = slot >> 3, c = slot & 7;
            gld16(A + (size_t)(m0 + r) * K + kt * 64 + ((c ^ (r & 7)) << 3),
                  &As[buf][0] + (size_t)(u * 512 + wave * 64) * 8);
        }
    };
    auto stageBh = [&](int kt, int buf, int h) {  // 2 gld16: B half h (128 rows)
#pragma unroll
        for (int u = 0; u < 2; u++) {
            int slot = (h * 2 + u) * 512 + wave * 64 + lane;
            int r = slot >> 3, c = slot & 7;
            gld16(B + (size_t)(n0 + r) * K + kt * 64 + ((c ^ (r & 7)) << 3),
                  &Bs[buf][0] + (size_t)((h * 2 + u) * 512 + wave * 64) * 8);
        }
    };

    // prologue: stage K-tiles 0 and 1 (12 loads); wait for tile 0's 6.
    stageA(0, 0); stageBh(0, 0, 0); stageBh(0, 0, 1);
    stageA(1, 1); stageBh(1, 1, 0); stageBh(1, 1, 1);
    asm volatile("s_waitcnt vmcnt(6)" ::: "memory");
    __builtin_amdgcn_s_barrier();

    for (int t = 0; t < NT; t++) {
        int cur = t % 3;
        int pre = (t + 2) % 3;
        bool more = (t + 2) < NT;

        // ---- phase 0 (kk = 0, chunk j = quad) ----
        {
            bf16x8 af[4], bfr[4];
#pragma unroll
            for (int mt = 0; mt < 4; mt++) {
                int rA = wr * 64 + mt * 16 + lane15;
                af[mt] = *(bf16x8*)(&As[cur][0] + rA * 64 + ((quad ^ (rA & 7)) << 3));
            }
#pragma unroll
            for (int nt = 0; nt < 4; nt++) {
                int rB = wc * 64 + nt * 16 + lane15;
                bfr[nt] = *(bf16x8*)(&Bs[cur][0] + rB * 64 + ((quad ^ (rB & 7)) << 3));
            }
            if (more) { stageA(t + 2, pre); stageBh(t + 2, pre, 0); }
            __builtin_amdgcn_s_barrier();
            asm volatile("s_waitcnt lgkmcnt(0)" ::: "memory");
            __builtin_amdgcn_sched_barrier(0);
            __builtin_amdgcn_s_setprio(1);
#pragma unroll
            for (int mt = 0; mt < 4; mt++)
#pragma unroll
                for (int nt = 0; nt < 4; nt++)
                    acc[mt][nt] = __builtin_amdgcn_mfma_f32_16x16x32_bf16(
                        af[mt], bfr[nt], acc[mt][nt], 0, 0, 0);
            __builtin_amdgcn_s_setprio(0);
            __builtin_amdgcn_s_barrier();
        }

        // ---- phase 1 (kk = 1, chunk j = 4 + quad) ----
        {
            bf16x8 af[4], bfr[4];
#pragma unroll
            for (int mt = 0; mt < 4; mt++) {
                int rA = wr * 64 + mt * 16 + lane15;
                af[mt] = *(bf16x8*)(&As[cur][0] + rA * 64 + (((4 + quad) ^ (rA & 7)) << 3));
            }
#pragma unroll
            for (int nt = 0; nt < 4; nt++) {
                int rB = wc * 64 + nt * 16 + lane15;
                bfr[nt] = *(bf16x8*)(&Bs[cur][0] + rB * 64 + (((4 + quad) ^ (rB & 7)) << 3));
            }
            if (more) stageBh(t + 2, pre, 1);
            __builtin_amdgcn_s_barrier();
            asm volatile("s_waitcnt lgkmcnt(0)" ::: "memory");
            __builtin_amdgcn_sched_barrier(0);
            __builtin_amdgcn_s_setprio(1);
#pragma unroll
            for (int mt = 0; mt < 4; mt++)
#pragma unroll
                for (int nt = 0; nt < 4; nt++)
                    acc[mt][nt] = __builtin_amdgcn_mfma_f32_16x16x32_bf16(
                        af[mt], bfr[nt], acc[mt][nt], 0, 0, 0);
            __builtin_amdgcn_s_setprio(0);
            if (t + 1 < NT) {
                if (more) asm volatile("s_waitcnt vmcnt(6)" ::: "memory");
                else      asm volatile("s_waitcnt vmcnt(0)" ::: "memory");
            }
            __builtin_amdgcn_s_barrier();
        }
    }

    const float KLOG = 13.287712379549449f / 32.0f;  // log2(10000)/32

    if (mode == 9 && n0 >= 2048) {                     // q-rope (scaled)
        int hh = (n0 + wc * 64 - 2048) >> 6;
#pragma unroll
        for (int mt = 0; mt < 4; mt++) {
            int row = m0 + wr * 64 + mt * 16 + quad * 4;
#pragma unroll
            for (int nt = 0; nt < 2; nt++) {
                int i = nt * 16 + lane15;              // 0..31
                float inv = exp2f(-(float)i * KLOG);
#pragma unroll
                for (int r = 0; r < 4; r++) {
                    int tok = row + r;
                    float p = (float)positions[tok & (SLEN - 1)];
                    float sn, cs; sincosf(p * inv, &sn, &cs);
                    float t1 = acc[mt][nt][r], t2 = acc[mt][nt + 2][r];
                    size_t ob = (size_t)tok * 3072 + hh * 192 + 128;
                    o.a[ob + i]      = (__bf16)((t1 * cs - t2 * sn) * scale);
                    o.a[ob + 32 + i] = (__bf16)((t2 * cs + t1 * sn) * scale);
                }
            }
        }
        return;
    }

#pragma unroll
    for (int mt = 0; mt < 4; mt++) {
        int row = m0 + wr * 64 + mt * 16 + quad * 4;
#pragma unroll
        for (int nt = 0; nt < 4; nt++) {
            int col = n0 + wc * 64 + nt * 16 + lane15;
#pragma unroll
            for (int r = 0; r < 4; r++) {
                float v = acc[mt][nt][r];
                size_t rw = (size_t)(row + r);
                if (mode == 2) {
                    o.f[rw * N + col] = v;
                } else if (mode == 9) {
                    o.a[rw * 3072 + (col >> 7) * 192 + (col & 127)] =
                        (__bf16)(v * scale);
                } else {  // 10
                    if (col < 2048)
                        o.a[rw * 3072 + (col >> 7) * 192 + (col & 127)] = (__bf16)v;
                    else {
                        int d = col - 2048;
                        o.b[((size_t)d * 2 + (rw >> 11)) * 2048 + (rw & 2047)] = (__bf16)v;
                    }
                }
            }
        }
    }
}

// ---------------------------------------------------------------------------
// Causal flash attention, Q-tile 128 (4 waves x 32 q-rows), K/V-tile 64.
// Best-measured config (round 5, 99.4 us): v0 structure + T1 XCD grouping
// (all 16 q-tile blocks of a (b,h) on ONE XCD -> K/V L2-resident, FETCH
// 120->33 MB) + complementary (qt,15-qt) b-partner balance + setprio.
// ---------------------------------------------------------------------------
__global__ __launch_bounds__(256, 2)
void mla_attn(const __bf16* __restrict__ Q, const __bf16* __restrict__ K,
              const __bf16* __restrict__ Vt, __bf16* __restrict__ O) {
    __shared__ __bf16 Ks[64 * 192];
    __shared__ __bf16 Vs[128 * 64];
    __shared__ __bf16 Ps[4][32][72];
    int tid = threadIdx.x, wave = tid >> 6, lane = tid & 63;
    int lane15 = lane & 15, quad = lane >> 4;

    int lin = blockIdx.x + (blockIdx.y << 4) + (blockIdx.z << 8);
    int xcd = lin & 7, slot = lin >> 3;
    int x = slot & 15;
    int g = xcd + ((slot >> 4) << 3);
    int h = g & 15, b = g >> 4;

    int qt0 = (x & 1) ? (x >> 1) : (15 - (x >> 1));
    int qt = b ? (15 - qt0) : qt0;
    int q0 = qt * 128;
    const __bf16* Qb  = Q + (size_t)b * SLEN * 3072 + h * 192;
    const __bf16* Kb  = K + (size_t)b * SLEN * 3072 + h * 192;
    const __bf16* vtb = Vt + ((size_t)(h * 128) * 2 + b) * 2048;

    bf16x8 qf[2][6];
#pragma unroll
    for (int mt = 0; mt < 2; mt++) {
        int qrow = q0 + wave * 32 + mt * 16 + lane15;
#pragma unroll
        for (int kk = 0; kk < 6; kk++)
            qf[mt][kk] = *(const bf16x8*)(Qb + (size_t)qrow * 3072 + kk * 32 + quad * 8);
    }
    bf16x8 ones;
#pragma unroll
    for (int e = 0; e < 8; e++) ones[e] = (__bf16)1.0f;

    f32x4 o_acc[2][8] = {};
    float m_i[2][4], l_i[2][4];
#pragma unroll
    for (int mt = 0; mt < 2; mt++)
#pragma unroll
        for (int r = 0; r < 4; r++) { m_i[mt][r] = -3.0e38f; l_i[mt][r] = 0.0f; }

    for (int j0 = 0; j0 <= q0 + 64; j0 += 64) {
#pragma unroll
        for (int t = 0; t < 6; t++) {
            int sb = (wave * 6 + t) * 64;
            int slot2 = sb + lane;
            int r = slot2 / 24;
            int c = slot2 - r * 24;
            int cgk = (c & ~7) | ((c & 7) ^ (r & 7));
            gld16(Kb + (size_t)(j0 + r) * 3072 + cgk * 8, Ks + sb * 8);
        }
#pragma unroll
        for (int t = 0; t < 4; t++) {
            int sb = (wave * 4 + t) * 64;
            int slot2 = sb + lane;
            int r = slot2 >> 3, c = slot2 & 7;
            gld16(vtb + (size_t)r * 4096 + j0 + (c ^ (r & 7)) * 8, Vs + sb * 8);
        }
        __syncthreads();

        f32x4 acc[2][4] = {};
        __builtin_amdgcn_s_setprio(1);
#pragma unroll
        for (int kk = 0; kk < 6; kk++) {
#pragma unroll
            for (int nt = 0; nt < 4; nt++) {
                int n = nt * 16 + lane15;
                int j = kk * 4 + quad;
                int cl = (j & ~7) | ((j & 7) ^ (n & 7));
                bf16x8 kf = *(bf16x8*)(Ks + n * 192 + cl * 8);
#pragma unroll
                for (int mt = 0; mt < 2; mt++)
                    acc[mt][nt] = __builtin_amdgcn_mfma_f32_16x16x32_bf16(
                        qf[mt][kk], kf, acc[mt][nt], 0, 0, 0);
            }
        }
        __builtin_amdgcn_s_setprio(0);

        if (j0 >= q0) {
#pragma unroll
            for (int mt = 0; mt < 2; mt++) {
                int rowg = q0 + wave * 32 + mt * 16 + quad * 4;
#pragma unroll
                for (int nt = 0; nt < 4; nt++) {
                    int colg = j0 + nt * 16 + lane15;
#pragma unroll
                    for (int r = 0; r < 4; r++)
                        if (colg > rowg + r) acc[mt][nt][r] = -3.0e38f;
                }
            }
        }

        float mx[2][4];
        bool need = false;
#pragma unroll
        for (int mt = 0; mt < 2; mt++)
#pragma unroll
            for (int r = 0; r < 4; r++) {
                float v = fmaxf(fmaxf(acc[mt][0][r], acc[mt][1][r]),
                                fmaxf(acc[mt][2][r], acc[mt][3][r]));
                mx[mt][r] = v;
                need = need || (v > m_i[mt][r] + 24.0f);
            }
        if (__any(need)) {
#pragma unroll
            for (int mt = 0; mt < 2; mt++)
#pragma unroll
                for (int r = 0; r < 4; r++) {
                    float v = mx[mt][r];
#pragma unroll
                    for (int d = 8; d >= 1; d >>= 1) v = fmaxf(v, __shfl_xor(v, d));
                    float mn = fmaxf(m_i[mt][r], v);
                    float alpha = exp2f(m_i[mt][r] - mn);
                    m_i[mt][r] = mn;
                    l_i[mt][r] *= alpha;
#pragma unroll
                    for (int nt = 0; nt < 8; nt++) o_acc[mt][nt][r] *= alpha;
                }
        }

#pragma unroll
        for (int mt = 0; mt < 2; mt++)
#pragma unroll
            for (int r = 0; r < 4; r++)
#pragma unroll
                for (int nt = 0; nt < 4; nt++) {
                    float pp = exp2f(acc[mt][nt][r] - m_i[mt][r]);
                    Ps[wave][mt * 16 + quad * 4 + r][nt * 16 + lane15] = (__bf16)pp;
                }

        f32x4 rs[2] = {};
        __builtin_amdgcn_s_setprio(1);
#pragma unroll
        for (int ks = 0; ks < 2; ks++) {
            bf16x8 pf[2];
#pragma unroll
            for (int mt = 0; mt < 2; mt++)
                pf[mt] = *(bf16x8*)(&Ps[wave][mt * 16 + lane15][ks * 32 + quad * 8]);
#pragma unroll
            for (int nt = 0; nt < 8; nt++) {
                int nn = nt * 16 + lane15;
                int j = ks * 4 + quad;
                bf16x8 vf = *(bf16x8*)(Vs + nn * 64 + (j ^ (nn & 7)) * 8);
#pragma unroll
                for (int mt = 0; mt < 2; mt++)
                    o_acc[mt][nt] = __builtin_amdgcn_mfma_f32_16x16x32_bf16(
                        pf[mt], vf, o_acc[mt][nt], 0, 0, 0);
            }
#pragma unroll
            for (int mt = 0; mt < 2; mt++)
                rs[mt] = __builtin_amdgcn_mfma_f32_16x16x32_bf16(
                    pf[mt], ones, rs[mt], 0, 0, 0);
        }
        __builtin_amdgcn_s_setprio(0);
#pragma unroll
        for (int mt = 0; mt < 2; mt++)
#pragma unroll
            for (int r = 0; r < 4; r++) l_i[mt][r] += rs[mt][r];
        __syncthreads();
    }

    int tokb = b * SLEN + q0 + wave * 32 + quad * 4;
#pragma unroll
    for (int mt = 0; mt < 2; mt++) {
#pragma unroll
        for (int r = 0; r < 4; r++) {
            float inv_l = 1.0f / l_i[mt][r];
            int tok = tokb + mt * 16 + r;
#pragma unroll
            for (int nt = 0; nt < 8; nt++) {
                O[(size_t)tok * 2048 + h * 128 + nt * 16 + lane15] =
                    (__bf16)(o_acc[mt][nt][r] * inv_l);
            }
        }
    }
}

// ---------------------------------------------------------------------------
extern "C" void kernel_launch(void* const* d_in, const int* in_sizes, int n_in,
                              void* d_out, int out_size, void* d_ws, size_t ws_size,
                              hipStream_t stream) {
    (void)in_sizes; (void)n_in; (void)out_size; (void)ws_size;
    const int* pos = (const int*)d_in[1];
    float* out = (float*)d_out;

    char* ws = (char*)d_ws;
    size_t off = 0;
    auto alloc = [&](size_t bytes) {
        char* p = ws + off;
        off += (bytes + 255) & ~(size_t)255;
        return p;
    };
    __bf16* x_bf  = (__bf16*)alloc(8388608ull * 2);
    __bf16* Wcat1 = (__bf16*)alloc(4325376ull * 2);  // Wqd | Wkvd | Wkr  (K=2048)
    __bf16* Wcat2 = (__bf16*)alloc(4718592ull * 2);  // Wqu | Wqr        (K=1536)
    __bf16* Wcat3 = (__bf16*)alloc(4194304ull * 2);  // Wku | Wvu        (K=512)
    __bf16* Wob   = (__bf16*)alloc(4194304ull * 2);
    __bf16* c_q   = (__bf16*)alloc(4096ull * 1536 * 2);
    __bf16* c_kv  = (__bf16*)alloc(4096ull * 512 * 2);
    __bf16* v_t   = (__bf16*)alloc(4096ull * 2048 * 2);
    __bf16* q_all = (__bf16*)alloc(4096ull * 3072 * 2);
    __bf16* k_all = (__bf16*)alloc(4096ull * 3072 * 2);
    __bf16* attn_o = (__bf16*)c_q;   // overlays c_q+c_kv (exactly 16.78 MB)

    const float scale_l2 = 1.4426950408889634f / sqrtf(192.0f);
    dim3 blk(256);
    dim3 blk8(512);

    CvArgs cv;
    cv.src[0] = (const float*)d_in[0]; cv.dst[0] = x_bf;
    cv.src[1] = (const float*)d_in[2]; cv.dst[1] = Wcat1;
    cv.src[2] = (const float*)d_in[5]; cv.dst[2] = Wcat1 + 3145728;
    cv.src[3] = (const float*)d_in[8]; cv.dst[3] = Wcat1 + 4194304;
    cv.src[4] = (const float*)d_in[3]; cv.dst[4] = Wcat2;
    cv.src[5] = (const float*)d_in[4]; cv.dst[5] = Wcat2 + 3145728;
    cv.src[6] = (const float*)d_in[6]; cv.dst[6] = Wcat3;
    cv.src[7] = (const float*)d_in[7]; cv.dst[7] = Wcat3 + 1048576;
    cv.src[8] = (const float*)d_in[9]; cv.dst[8] = Wob;
    long ns[9] = {8388608, 3145728, 1048576, 131072, 3145728, 1572864,
                  1048576, 1048576, 4194304};
    cv.cum[0] = 0;
    for (int i = 0; i < 9; i++) cv.cum[i + 1] = cv.cum[i] + ns[i];
    convert_all<<<dim3((unsigned)(cv.cum[9] / 2048)), blk, 0, stream>>>(cv);

    // gemm1: x @ [Wqd|Wkvd|Wkr]^T (N=2112 incl rope strip) — old kernel
    Outs o1 = { c_q, c_kv, k_all, nullptr };
    gemm_nt<<<dim3(32, 17), blk, 0, stream>>>(x_bf, Wcat1, o1, pos, 4096, 2112, 2048, 8, 1.0f);
    // gemm2: c_q @ [Wqu|Wqr]^T -> q_all (+rope)   N=3072, K=1536, 384 blocks
    Outs o2 = { q_all, nullptr, nullptr, nullptr };
    gemm8p<<<dim3(384), blk8, 0, stream>>>(c_q, Wcat2, o2, pos, 3072, 1536, 9, scale_l2);
    // gemm3: c_kv @ [Wku|Wvu]^T -> k_all + v_t    N=4096, K=512, 512 blocks
    Outs o3 = { k_all, v_t, nullptr, nullptr };
    gemm8p<<<dim3(512), blk8, 0, stream>>>(c_kv, Wcat3, o3, pos, 4096, 512, 10, 1.0f);
    mla_attn<<<dim3(16, 16, 2), blk, 0, stream>>>(q_all, k_all, v_t, attn_o);
    // gemm4: attn_o @ Wo^T -> out fp32            N=2048, K=2048, 256 blocks
    Outs o4 = { nullptr, nullptr, nullptr, out };
    gemm8p<<<dim3(256), blk8, 0, stream>>>(attn_o, Wob, o4, pos, 2048, 2048, 2, 1.0f);
}

// Round 9
// 429.038 us; speedup vs baseline: 1.0663x; 1.0663x over previous
//
#include <hip/hip_runtime.h>
#include <cmath>

#define SLEN 2048

typedef __bf16 bf16x8 __attribute__((ext_vector_type(8)));
typedef float  f32x4  __attribute__((ext_vector_type(4)));

__device__ inline void gld16(const void* g, void* l) {
    __builtin_amdgcn_global_load_lds(
        (const __attribute__((address_space(1))) void*)(uintptr_t)g,
        (__attribute__((address_space(3))) void*)(unsigned)(uintptr_t)l, 16, 0, 0);
}

// ---------------------------------------------------------------------------
// One-launch fp32->bf16 convert of all 9 inputs (segment table by value).
// ---------------------------------------------------------------------------
struct CvArgs {
    const float* src[9];
    __bf16*      dst[9];
    long         cum[10];
};
__global__ __launch_bounds__(256)
void convert_all(CvArgs a) {
    long i8 = ((long)blockIdx.x * 256 + threadIdx.x) * 8;
    if (i8 >= a.cum[9]) return;
    int s = 0;
#pragma unroll
    for (int k = 1; k < 9; k++) if (i8 >= a.cum[k]) s = k;
    long loc = i8 - a.cum[s];
    const float* sp = a.src[s] + loc;
    float4 u0 = *(const float4*)(sp);
    float4 u1 = *(const float4*)(sp + 4);
    bf16x8 o;
    o[0] = (__bf16)u0.x; o[1] = (__bf16)u0.y; o[2] = (__bf16)u0.z; o[3] = (__bf16)u0.w;
    o[4] = (__bf16)u1.x; o[5] = (__bf16)u1.y; o[6] = (__bf16)u1.z; o[7] = (__bf16)u1.w;
    *(bf16x8*)(a.dst[s] + loc) = o;
}

// ---------------------------------------------------------------------------
// NT GEMM body, 128x128x64 tiles, 4 waves, global_load_lds + XOR-swizzled
// LDS — the proven v0 structure, verbatim, factored so two kernels share it.
// Epilogue modes:
//  2: fp32 [M,N] row-major (final output)
//  8: down-proj merged: col<1536 -> c_q; col<2048 -> c_kv; tile n0==2048 ->
//     k-rope (rotate pairs i/i+32, broadcast 16 heads into k_all)
//  9: up-Q merged (scaled by `scale`): col<2048 -> q_all nope scatter;
//     col>=2048 -> q-rope into q_all[...,128:192]
// 10: up-KV merged: col<2048 -> k_all nope scatter; col>=2048 -> V transpose
// ---------------------------------------------------------------------------
struct Outs { __bf16* a; __bf16* b; __bf16* c; float* f; };

__device__ __forceinline__ void gemm_body(
    const __bf16* __restrict__ A, const __bf16* __restrict__ B,
    Outs o, const int* __restrict__ positions,
    int N, int K, int mode, float scale, int m0, int n0,
    __bf16* As, __bf16* Bs)
{
    int tid = threadIdx.x;
    int wave = tid >> 6, lane = tid & 63;
    int lane15 = lane & 15, quad = lane >> 4;
    int ri = lane >> 3, ci = lane & 7;
    int cg = ci ^ ri;
    int wm = (wave & 1) * 64, wn = (wave >> 1) * 64;
    f32x4 acc[4][4] = {};

    for (int k0 = 0; k0 < K; k0 += 64) {
#pragma unroll
        for (int t = 0; t < 4; t++) {
            int rr = wave * 32 + t * 8;
            int r = rr + ri;
            gld16(A + (size_t)(m0 + r) * K + k0 + cg * 8, As + rr * 64);
            int br = n0 + r; if (br > N - 1) br = N - 1;
            gld16(B + (size_t)br * K + k0 + cg * 8, Bs + rr * 64);
        }
        __syncthreads();
#pragma unroll
        for (int kk = 0; kk < 64; kk += 32) {
            int jb = kk >> 3;
            bf16x8 af[4], bfr[4];
#pragma unroll
            for (int mt = 0; mt < 4; mt++) {
                int rA = wm + mt * 16 + lane15;
                af[mt] = *(bf16x8*)(As + rA * 64 + (((jb + quad) ^ (rA & 7)) << 3));
            }
#pragma unroll
            for (int nt = 0; nt < 4; nt++) {
                int rB = wn + nt * 16 + lane15;
                bfr[nt] = *(bf16x8*)(Bs + rB * 64 + (((jb + quad) ^ (rB & 7)) << 3));
            }
#pragma unroll
            for (int mt = 0; mt < 4; mt++)
#pragma unroll
                for (int nt = 0; nt < 4; nt++)
                    acc[mt][nt] = __builtin_amdgcn_mfma_f32_16x16x32_bf16(
                        af[mt], bfr[nt], acc[mt][nt], 0, 0, 0);
        }
        __syncthreads();
    }

    const float KLOG = 13.287712379549449f / 32.0f;  // log2(10000)/32

    // --- rope tiles -------------------------------------------------------
    if (mode == 8 && n0 == 2048) {                     // k-rope + broadcast
        if (wn == 0) {
#pragma unroll
            for (int mt = 0; mt < 4; mt++) {
                int row = m0 + wm + mt * 16 + quad * 4;
#pragma unroll
                for (int nt = 0; nt < 2; nt++) {
                    int i = nt * 16 + lane15;          // 0..31
                    float inv = exp2f(-(float)i * KLOG);
#pragma unroll
                    for (int r = 0; r < 4; r++) {
                        int tok = row + r;
                        float p = (float)positions[tok & (SLEN - 1)];
                        float sn, cs; sincosf(p * inv, &sn, &cs);
                        float t1 = acc[mt][nt][r], t2 = acc[mt][nt + 2][r];
                        float rot1 = t1 * cs - t2 * sn;
                        float rot2 = t2 * cs + t1 * sn;
                        size_t ob = (size_t)tok * 3072 + 128;
#pragma unroll
                        for (int hh = 0; hh < 16; hh++) {
                            o.c[ob + hh * 192 + i]      = (__bf16)rot1;
                            o.c[ob + hh * 192 + 32 + i] = (__bf16)rot2;
                        }
                    }
                }
            }
        }
        return;
    }
    if (mode == 9 && n0 >= 2048) {                     // q-rope (scaled)
        int hh = (n0 + wn - 2048) >> 6;
#pragma unroll
        for (int mt = 0; mt < 4; mt++) {
            int row = m0 + wm + mt * 16 + quad * 4;
#pragma unroll
            for (int nt = 0; nt < 2; nt++) {
                int i = nt * 16 + lane15;              // 0..31
                float inv = exp2f(-(float)i * KLOG);
#pragma unroll
                for (int r = 0; r < 4; r++) {
                    int tok = row + r;
                    float p = (float)positions[tok & (SLEN - 1)];
                    float sn, cs; sincosf(p * inv, &sn, &cs);
                    float t1 = acc[mt][nt][r], t2 = acc[mt][nt + 2][r];
                    size_t ob = (size_t)tok * 3072 + hh * 192 + 128;
                    o.a[ob + i]      = (__bf16)((t1 * cs - t2 * sn) * scale);
                    o.a[ob + 32 + i] = (__bf16)((t2 * cs + t1 * sn) * scale);
                }
            }
        }
        return;
    }

    // --- generic epilogues ------------------------------------------------
#pragma unroll
    for (int mt = 0; mt < 4; mt++) {
        int row = m0 + wm + mt * 16 + quad * 4;
#pragma unroll
        for (int nt = 0; nt < 4; nt++) {
            int col = n0 + wn + nt * 16 + lane15;
            if (col < N) {
#pragma unroll
                for (int r = 0; r < 4; r++) {
                    float v = acc[mt][nt][r];
                    size_t rw = (size_t)(row + r);
                    if (mode == 2) {
                        o.f[rw * N + col] = v;
                    } else if (mode == 8) {
                        if (col < 1536) o.a[rw * 1536 + col] = (__bf16)v;
                        else            o.b[rw * 512 + col - 1536] = (__bf16)v;
                    } else if (mode == 9) {
                        o.a[rw * 3072 + (col >> 7) * 192 + (col & 127)] =
                            (__bf16)(v * scale);
                    } else {  // 10
                        if (col < 2048)
                            o.a[rw * 3072 + (col >> 7) * 192 + (col & 127)] = (__bf16)v;
                        else {
                            int d = col - 2048;
                            o.b[((size_t)d * 2 + (rw >> 11)) * 2048 + (rw & 2047)] = (__bf16)v;
                        }
                    }
                }
            }
        }
    }
}

__global__ __launch_bounds__(256, 3)
void gemm_nt(const __bf16* __restrict__ A, const __bf16* __restrict__ B,
             Outs o, const int* __restrict__ positions,
             int N, int K, int mode, float scale) {
    __shared__ __bf16 As[128 * 64];
    __shared__ __bf16 Bs[128 * 64];
    gemm_body(A, B, o, positions, N, K, mode, scale,
              blockIdx.x * 128, blockIdx.y * 128, As, Bs);
}

// ---------------------------------------------------------------------------
// Merged gemm2+gemm3 dispatch: both depend only on gemm1 and write disjoint
// outputs, so their blocks can share one launch.  1792 = 7*256 blocks:
// bid%7<3 -> gemm2 (768 blocks, N=3072 K=1536 mode 9), else gemm3 (1024
// blocks, N=4096 K=512 mode 10).  Interleaving lets gemm3's barrier-stalled
// small-K blocks co-schedule with gemm2's compute (m114 cross-block overlap),
// and removes one launch boundary + tail drain.
// ---------------------------------------------------------------------------
__global__ __launch_bounds__(256, 3)
void gemm_dual(const __bf16* __restrict__ A2, const __bf16* __restrict__ B2, Outs o2,
               const __bf16* __restrict__ A3, const __bf16* __restrict__ B3, Outs o3,
               const int* __restrict__ positions, float scale2) {
    __shared__ __bf16 As[128 * 64];
    __shared__ __bf16 Bs[128 * 64];
    int bid = blockIdx.x;
    int q = bid / 7, rr = bid % 7;
    if (rr < 3) {
        int idx = q * 3 + rr;                   // 0..767
        gemm_body(A2, B2, o2, positions, 3072, 1536, 9, scale2,
                  (idx & 31) * 128, (idx >> 5) * 128, As, Bs);
    } else {
        int idx = q * 4 + (rr - 3);             // 0..1023
        gemm_body(A3, B3, o3, positions, 4096, 512, 10, 1.0f,
                  (idx & 31) * 128, (idx >> 5) * 128, As, Bs);
    }
}

// ---------------------------------------------------------------------------
// Causal flash attention, Q-tile 128 (4 waves x 32 q-rows), K/V-tile 64.
// Best-measured config (98.9 us, round 8): v0 structure + T1 XCD grouping
// (all 16 q-tile blocks of a (b,h) on ONE XCD -> K/V L2-resident, FETCH
// 120->33 MB) + complementary (qt,15-qt) b-partner balance + setprio.
// ---------------------------------------------------------------------------
__global__ __launch_bounds__(256, 2)
void mla_attn(const __bf16* __restrict__ Q, const __bf16* __restrict__ K,
              const __bf16* __restrict__ Vt, __bf16* __restrict__ O) {
    __shared__ __bf16 Ks[64 * 192];
    __shared__ __bf16 Vs[128 * 64];
    __shared__ __bf16 Ps[4][32][72];
    int tid = threadIdx.x, wave = tid >> 6, lane = tid & 63;
    int lane15 = lane & 15, quad = lane >> 4;

    int lin = blockIdx.x + (blockIdx.y << 4) + (blockIdx.z << 8);
    int xcd = lin & 7, slot = lin >> 3;
    int x = slot & 15;
    int g = xcd + ((slot >> 4) << 3);
    int h = g & 15, b = g >> 4;

    int qt0 = (x & 1) ? (x >> 1) : (15 - (x >> 1));
    int qt = b ? (15 - qt0) : qt0;
    int q0 = qt * 128;
    const __bf16* Qb  = Q + (size_t)b * SLEN * 3072 + h * 192;
    const __bf16* Kb  = K + (size_t)b * SLEN * 3072 + h * 192;
    const __bf16* vtb = Vt + ((size_t)(h * 128) * 2 + b) * 2048;

    bf16x8 qf[2][6];
#pragma unroll
    for (int mt = 0; mt < 2; mt++) {
        int qrow = q0 + wave * 32 + mt * 16 + lane15;
#pragma unroll
        for (int kk = 0; kk < 6; kk++)
            qf[mt][kk] = *(const bf16x8*)(Qb + (size_t)qrow * 3072 + kk * 32 + quad * 8);
    }
    bf16x8 ones;
#pragma unroll
    for (int e = 0; e < 8; e++) ones[e] = (__bf16)1.0f;

    f32x4 o_acc[2][8] = {};
    float m_i[2][4], l_i[2][4];
#pragma unroll
    for (int mt = 0; mt < 2; mt++)
#pragma unroll
        for (int r = 0; r < 4; r++) { m_i[mt][r] = -3.0e38f; l_i[mt][r] = 0.0f; }

    for (int j0 = 0; j0 <= q0 + 64; j0 += 64) {
#pragma unroll
        for (int t = 0; t < 6; t++) {
            int sb = (wave * 6 + t) * 64;
            int slot2 = sb + lane;
            int r = slot2 / 24;
            int c = slot2 - r * 24;
            int cgk = (c & ~7) | ((c & 7) ^ (r & 7));
            gld16(Kb + (size_t)(j0 + r) * 3072 + cgk * 8, Ks + sb * 8);
        }
#pragma unroll
        for (int t = 0; t < 4; t++) {
            int sb = (wave * 4 + t) * 64;
            int slot2 = sb + lane;
            int r = slot2 >> 3, c = slot2 & 7;
            gld16(vtb + (size_t)r * 4096 + j0 + (c ^ (r & 7)) * 8, Vs + sb * 8);
        }
        __syncthreads();

        f32x4 acc[2][4] = {};
        __builtin_amdgcn_s_setprio(1);
#pragma unroll
        for (int kk = 0; kk < 6; kk++) {
#pragma unroll
            for (int nt = 0; nt < 4; nt++) {
                int n = nt * 16 + lane15;
                int j = kk * 4 + quad;
                int cl = (j & ~7) | ((j & 7) ^ (n & 7));
                bf16x8 kf = *(bf16x8*)(Ks + n * 192 + cl * 8);
#pragma unroll
                for (int mt = 0; mt < 2; mt++)
                    acc[mt][nt] = __builtin_amdgcn_mfma_f32_16x16x32_bf16(
                        qf[mt][kk], kf, acc[mt][nt], 0, 0, 0);
            }
        }
        __builtin_amdgcn_s_setprio(0);

        if (j0 >= q0) {
#pragma unroll
            for (int mt = 0; mt < 2; mt++) {
                int rowg = q0 + wave * 32 + mt * 16 + quad * 4;
#pragma unroll
                for (int nt = 0; nt < 4; nt++) {
                    int colg = j0 + nt * 16 + lane15;
#pragma unroll
                    for (int r = 0; r < 4; r++)
                        if (colg > rowg + r) acc[mt][nt][r] = -3.0e38f;
                }
            }
        }

        float mx[2][4];
        bool need = false;
#pragma unroll
        for (int mt = 0; mt < 2; mt++)
#pragma unroll
            for (int r = 0; r < 4; r++) {
                float v = fmaxf(fmaxf(acc[mt][0][r], acc[mt][1][r]),
                                fmaxf(acc[mt][2][r], acc[mt][3][r]));
                mx[mt][r] = v;
                need = need || (v > m_i[mt][r] + 24.0f);
            }
        if (__any(need)) {
#pragma unroll
            for (int mt = 0; mt < 2; mt++)
#pragma unroll
                for (int r = 0; r < 4; r++) {
                    float v = mx[mt][r];
#pragma unroll
                    for (int d = 8; d >= 1; d >>= 1) v = fmaxf(v, __shfl_xor(v, d));
                    float mn = fmaxf(m_i[mt][r], v);
                    float alpha = exp2f(m_i[mt][r] - mn);
                    m_i[mt][r] = mn;
                    l_i[mt][r] *= alpha;
#pragma unroll
                    for (int nt = 0; nt < 8; nt++) o_acc[mt][nt][r] *= alpha;
                }
        }

#pragma unroll
        for (int mt = 0; mt < 2; mt++)
#pragma unroll
            for (int r = 0; r < 4; r++)
#pragma unroll
                for (int nt = 0; nt < 4; nt++) {
                    float pp = exp2f(acc[mt][nt][r] - m_i[mt][r]);
                    Ps[wave][mt * 16 + quad * 4 + r][nt * 16 + lane15] = (__bf16)pp;
                }

        f32x4 rs[2] = {};
        __builtin_amdgcn_s_setprio(1);
#pragma unroll
        for (int ks = 0; ks < 2; ks++) {
            bf16x8 pf[2];
#pragma unroll
            for (int mt = 0; mt < 2; mt++)
                pf[mt] = *(bf16x8*)(&Ps[wave][mt * 16 + lane15][ks * 32 + quad * 8]);
#pragma unroll
            for (int nt = 0; nt < 8; nt++) {
                int nn = nt * 16 + lane15;
                int j = ks * 4 + quad;
                bf16x8 vf = *(bf16x8*)(Vs + nn * 64 + (j ^ (nn & 7)) * 8);
#pragma unroll
                for (int mt = 0; mt < 2; mt++)
                    o_acc[mt][nt] = __builtin_amdgcn_mfma_f32_16x16x32_bf16(
                        pf[mt], vf, o_acc[mt][nt], 0, 0, 0);
            }
#pragma unroll
            for (int mt = 0; mt < 2; mt++)
                rs[mt] = __builtin_amdgcn_mfma_f32_16x16x32_bf16(
                    pf[mt], ones, rs[mt], 0, 0, 0);
        }
        __builtin_amdgcn_s_setprio(0);
#pragma unroll
        for (int mt = 0; mt < 2; mt++)
#pragma unroll
            for (int r = 0; r < 4; r++) l_i[mt][r] += rs[mt][r];
        __syncthreads();
    }

    int tokb = b * SLEN + q0 + wave * 32 + quad * 4;
#pragma unroll
    for (int mt = 0; mt < 2; mt++) {
#pragma unroll
        for (int r = 0; r < 4; r++) {
            float inv_l = 1.0f / l_i[mt][r];
            int tok = tokb + mt * 16 + r;
#pragma unroll
            for (int nt = 0; nt < 8; nt++) {
                O[(size_t)tok * 2048 + h * 128 + nt * 16 + lane15] =
                    (__bf16)(o_acc[mt][nt][r] * inv_l);
            }
        }
    }
}

// ---------------------------------------------------------------------------
extern "C" void kernel_launch(void* const* d_in, const int* in_sizes, int n_in,
                              void* d_out, int out_size, void* d_ws, size_t ws_size,
                              hipStream_t stream) {
    (void)in_sizes; (void)n_in; (void)out_size; (void)ws_size;
    const int* pos = (const int*)d_in[1];
    float* out = (float*)d_out;

    char* ws = (char*)d_ws;
    size_t off = 0;
    auto alloc = [&](size_t bytes) {
        char* p = ws + off;
        off += (bytes + 255) & ~(size_t)255;
        return p;
    };
    __bf16* x_bf  = (__bf16*)alloc(8388608ull * 2);
    __bf16* Wcat1 = (__bf16*)alloc(4325376ull * 2);  // Wqd | Wkvd | Wkr  (K=2048)
    __bf16* Wcat2 = (__bf16*)alloc(4718592ull * 2);  // Wqu | Wqr        (K=1536)
    __bf16* Wcat3 = (__bf16*)alloc(4194304ull * 2);  // Wku | Wvu        (K=512)
    __bf16* Wob   = (__bf16*)alloc(4194304ull * 2);
    __bf16* c_q   = (__bf16*)alloc(4096ull * 1536 * 2);
    __bf16* c_kv  = (__bf16*)alloc(4096ull * 512 * 2);
    __bf16* v_t   = (__bf16*)alloc(4096ull * 2048 * 2);
    __bf16* q_all = (__bf16*)alloc(4096ull * 3072 * 2);
    __bf16* k_all = (__bf16*)alloc(4096ull * 3072 * 2);
    __bf16* attn_o = (__bf16*)c_q;   // overlays c_q+c_kv (exactly 16.78 MB)

    const float scale_l2 = 1.4426950408889634f / sqrtf(192.0f);
    dim3 blk(256);

    CvArgs cv;
    cv.src[0] = (const float*)d_in[0]; cv.dst[0] = x_bf;
    cv.src[1] = (const float*)d_in[2]; cv.dst[1] = Wcat1;
    cv.src[2] = (const float*)d_in[5]; cv.dst[2] = Wcat1 + 3145728;
    cv.src[3] = (const float*)d_in[8]; cv.dst[3] = Wcat1 + 4194304;
    cv.src[4] = (const float*)d_in[3]; cv.dst[4] = Wcat2;
    cv.src[5] = (const float*)d_in[4]; cv.dst[5] = Wcat2 + 3145728;
    cv.src[6] = (const float*)d_in[6]; cv.dst[6] = Wcat3;
    cv.src[7] = (const float*)d_in[7]; cv.dst[7] = Wcat3 + 1048576;
    cv.src[8] = (const float*)d_in[9]; cv.dst[8] = Wob;
    long ns[9] = {8388608, 3145728, 1048576, 131072, 3145728, 1572864,
                  1048576, 1048576, 4194304};
    cv.cum[0] = 0;
    for (int i = 0; i < 9; i++) cv.cum[i + 1] = cv.cum[i] + ns[i];
    convert_all<<<dim3((unsigned)(cv.cum[9] / 2048)), blk, 0, stream>>>(cv);

    // gemm1: x @ [Wqd|Wkvd|Wkr]^T -> c_q | c_kv | k-rope broadcast
    Outs o1 = { c_q, c_kv, k_all, nullptr };
    gemm_nt<<<dim3(32, 17), blk, 0, stream>>>(x_bf, Wcat1, o1, pos, 2112, 2048, 8, 1.0f);
    // merged gemm2+gemm3 (independent of each other, both depend on gemm1)
    Outs o2 = { q_all, nullptr, nullptr, nullptr };
    Outs o3 = { k_all, v_t, nullptr, nullptr };
    gemm_dual<<<dim3(1792), blk, 0, stream>>>(c_q, Wcat2, o2, c_kv, Wcat3, o3, pos, scale_l2);
    mla_attn<<<dim3(16, 16, 2), blk, 0, stream>>>(q_all, k_all, v_t, attn_o);
    // gemm4: attn_o @ Wo^T -> out fp32
    Outs o4 = { nullptr, nullptr, nullptr, out };
    gemm_nt<<<dim3(32, 16), blk, 0, stream>>>(attn_o, Wob, o4, pos, 2048, 2048, 2, 1.0f);
}